// Round 1
// baseline (1227.387 us; speedup 1.0000x reference)
//
#include <hip/hip_runtime.h>

typedef unsigned short u16;
typedef unsigned int   u32;
typedef __attribute__((ext_vector_type(8))) short  short8;
typedef __attribute__((ext_vector_type(8))) u16    ushort8;
typedef __attribute__((ext_vector_type(4))) u16    ushort4v;
typedef __attribute__((ext_vector_type(4))) float  f32x4;

#define AS1 __attribute__((address_space(1)))
#define AS3 __attribute__((address_space(3)))

__device__ __forceinline__ float bf2f(u16 u) {
    union { u32 i; float f; } x; x.i = ((u32)u) << 16; return x.f;
}
__device__ __forceinline__ u16 f2bf(float f) {
    union { float f; u32 i; } x; x.f = f;
    u32 r = x.i + 0x7fffu + ((x.i >> 16) & 1u);
    return (u16)(r >> 16);
}

// ---------------------------------------------------------------- prep kernels

__global__ __launch_bounds__(256) void k_transpose_cast(
    const float* __restrict__ src, u16* __restrict__ dst, int R, int C)
{
    int i = blockIdx.x * 256 + threadIdx.x;
    if (i >= R * C) return;
    int r = i / C, c = i - r * C;
    dst[(size_t)c * R + r] = f2bf(src[i]);
}

__global__ __launch_bounds__(256) void k_cast8(
    const float* __restrict__ src, u16* __restrict__ dst)
{
    size_t i = ((size_t)blockIdx.x * 256 + threadIdx.x) * 8;
    float4 a = *(const float4*)(src + i);
    float4 b = *(const float4*)(src + i + 4);
    ushort8 o;
    o[0] = f2bf(a.x); o[1] = f2bf(a.y); o[2] = f2bf(a.z); o[3] = f2bf(a.w);
    o[4] = f2bf(b.x); o[5] = f2bf(b.y); o[6] = f2bf(b.z); o[7] = f2bf(b.w);
    *(ushort8*)(dst + i) = o;
}

// one wave per key vector (256 floats); 4 keys per block
__global__ __launch_bounds__(256) void k_norm_keys(
    const float* __restrict__ keys, u16* __restrict__ kn)
{
    int key  = blockIdx.x * 4 + (threadIdx.x >> 6);
    int lane = threadIdx.x & 63;
    const float* kp = keys + (size_t)key * 256 + lane * 4;
    float4 v = *(const float4*)kp;
    float ss = v.x * v.x + v.y * v.y + v.z * v.z + v.w * v.w;
#pragma unroll
    for (int o = 32; o; o >>= 1) ss += __shfl_xor(ss, o);
    float sc = 1.0f / sqrtf(ss);
    ushort4v o4;
    o4[0] = f2bf(v.x * sc); o4[1] = f2bf(v.y * sc);
    o4[2] = f2bf(v.z * sc); o4[3] = f2bf(v.w * sc);
    *(ushort4v*)(kn + (size_t)key * 256 + lane * 4) = o4;
}

// ---------------------------------------------------------------- bf16 NT GEMM
// C(MxN) = A(MxK) * B(NxK)^T ; A,B bf16 row-major (K contiguous).
// EPI 0: store bf16, no bias. EPI 1: +bias, store bf16. EPI 2: +bias, store f32.
template<int EPI>
__global__ __launch_bounds__(256) void gemm_nt(
    const short* __restrict__ A, const short* __restrict__ B,
    void* __restrict__ Cp, const float* __restrict__ bias,
    int M, int N, int K, int ldc)
{
    __shared__ __align__(16) short lA[128 * 32];
    __shared__ __align__(16) short lB[128 * 32];
    const int t  = threadIdx.x;
    const int m0 = blockIdx.y << 7, n0 = blockIdx.x << 7;
    const int w  = t >> 6, lane = t & 63;
    const int wr = (w >> 1) << 6, wc = (w & 1) << 6;
    const int qr = lane & 15, qh = lane >> 4;

    f32x4 acc[4][4];
#pragma unroll
    for (int i = 0; i < 4; ++i)
#pragma unroll
        for (int j = 0; j < 4; ++j) acc[i][j] = (f32x4){0.f, 0.f, 0.f, 0.f};

    const short* ga0 = A + (size_t)(m0 + (t >> 2)) * K + (t & 3) * 8;
    const short* ga1 = ga0 + (size_t)64 * K;
    const short* gb0 = B + (size_t)(n0 + (t >> 2)) * K + (t & 3) * 8;
    const short* gb1 = gb0 + (size_t)64 * K;
    char* lAb = (char*)lA + w * 1024;
    char* lBb = (char*)lB + w * 1024;

    for (int k0 = 0; k0 < K; k0 += 32) {
        __builtin_amdgcn_global_load_lds((const AS1 void*)(ga0 + k0), (AS3 void*)lAb,          16, 0, 0);
        __builtin_amdgcn_global_load_lds((const AS1 void*)(ga1 + k0), (AS3 void*)(lAb + 4096), 16, 0, 0);
        __builtin_amdgcn_global_load_lds((const AS1 void*)(gb0 + k0), (AS3 void*)lBb,          16, 0, 0);
        __builtin_amdgcn_global_load_lds((const AS1 void*)(gb1 + k0), (AS3 void*)(lBb + 4096), 16, 0, 0);
        __syncthreads();
        short8 af[4], bfr[4];
#pragma unroll
        for (int i = 0; i < 4; ++i) af[i]  = *(const short8*)&lA[(wr + i * 16 + qr) * 32 + qh * 8];
#pragma unroll
        for (int i = 0; i < 4; ++i) bfr[i] = *(const short8*)&lB[(wc + i * 16 + qr) * 32 + qh * 8];
#pragma unroll
        for (int mi = 0; mi < 4; ++mi)
#pragma unroll
            for (int ni = 0; ni < 4; ++ni)
                acc[mi][ni] = __builtin_amdgcn_mfma_f32_16x16x32_bf16(af[mi], bfr[ni], acc[mi][ni], 0, 0, 0);
        __syncthreads();
    }

#pragma unroll
    for (int mi = 0; mi < 4; ++mi)
#pragma unroll
        for (int ni = 0; ni < 4; ++ni) {
            const int col = n0 + wc + ni * 16 + qr;
            float bv = (EPI != 0) ? bias[col] : 0.f;
            f32x4 a = acc[mi][ni];
#pragma unroll
            for (int j = 0; j < 4; ++j) {
                const int row = m0 + wr + mi * 16 + qh * 4 + j;
                float v = a[j] + bv;
                if (EPI == 2) ((float*)Cp)[(size_t)row * ldc + col] = v;
                else          ((u16*)Cp)[(size_t)row * ldc + col]  = f2bf(v);
            }
        }
}

// ---------------------------------------------------------------- select+gather
// One block per row. Scores row (16384 bf16) kept in registers (64/thread).
// Threshold-compaction at ~0.55*rowmax, exact top-32 by iterated block argmax
// with (val desc, idx asc) order, softmax, weighted gather of values + residual.
#define CAP 4096

__global__ __launch_bounds__(256) void k_select(
    const u16* __restrict__ scores,   // CR x 16384 (bf16 bits)
    const void* __restrict__ vtab,    // slot value table (bf16 or f32)
    const float* __restrict__ res,    // BS x 512
    float* __restrict__ out,          // BS x 4 x 512
    int s, int r0, int useBf)
{
    __shared__ float cval[CAP];
    __shared__ int   cidx[CAP];
    __shared__ int   lcnt;
    __shared__ float rmax_s;
    __shared__ float wred[4];
    __shared__ int   wredi[4], wredp[4];
    __shared__ float topv[32], wts[32];
    __shared__ int   topi[32];

    const int t = threadIdx.x;
    const int row_l = blockIdx.x;
    const int row_b = r0 + row_l;
    const u16* srow = scores + (size_t)row_l * 16384;

    float sv[64];
    float m = -3.0e38f;
#pragma unroll
    for (int j = 0; j < 8; ++j) {
        ushort8 u = *(const ushort8*)(srow + (size_t)(j * 256 + t) * 8);
#pragma unroll
        for (int i = 0; i < 8; ++i) {
            float f = bf2f(u[i]);
            sv[j * 8 + i] = f;
            m = fmaxf(m, f);
        }
    }
#pragma unroll
    for (int o = 32; o; o >>= 1) m = fmaxf(m, __shfl_xor(m, o));
    if ((t & 63) == 0) wred[t >> 6] = m;
    __syncthreads();
    if (t == 0) rmax_s = fmaxf(fmaxf(wred[0], wred[1]), fmaxf(wred[2], wred[3]));
    __syncthreads();
    const float rmax = rmax_s;

    float thr = rmax - (0.45f * fabsf(rmax) + 1e-6f);
    int cnt = 0;
    for (int attempt = 0; ; ++attempt) {
        __syncthreads();
        if (t == 0) lcnt = 0;
        __syncthreads();
#pragma unroll
        for (int j = 0; j < 8; ++j)
#pragma unroll
            for (int i = 0; i < 8; ++i) {
                float f = sv[j * 8 + i];
                if (f >= thr) {
                    int p = atomicAdd(&lcnt, 1);
                    if (p < CAP) { cval[p] = f; cidx[p] = (j * 256 + t) * 8 + i; }
                }
            }
        __syncthreads();
        cnt = lcnt;
        if ((cnt >= 32 && cnt <= CAP) || attempt >= 12) {
            if (cnt > CAP) cnt = CAP;
            break;
        }
        if (cnt < 32) thr -= (0.35f * fabsf(rmax) + 0.25f);
        else          thr  = 0.5f * (thr + rmax);
    }

    // 32 x block-argmax over candidates
    for (int k = 0; k < 32; ++k) {
        float bv = -3.0e38f; int bi = 0x7fffffff; int bp = -1;
        for (int i = t; i < cnt; i += 256) {
            float v = cval[i]; int id = cidx[i];
            if (v > bv || (v == bv && id < bi)) { bv = v; bi = id; bp = i; }
        }
#pragma unroll
        for (int o = 32; o; o >>= 1) {
            float ov = __shfl_xor(bv, o);
            int   oi = __shfl_xor(bi, o);
            int   op = __shfl_xor(bp, o);
            if (ov > bv || (ov == bv && oi < bi)) { bv = ov; bi = oi; bp = op; }
        }
        if ((t & 63) == 0) { wred[t >> 6] = bv; wredi[t >> 6] = bi; wredp[t >> 6] = bp; }
        __syncthreads();
        if (t == 0) {
            float Bv = wred[0]; int Bi = wredi[0]; int Bp = wredp[0];
            for (int wdx = 1; wdx < 4; ++wdx)
                if (wred[wdx] > Bv || (wred[wdx] == Bv && wredi[wdx] < Bi)) {
                    Bv = wred[wdx]; Bi = wredi[wdx]; Bp = wredp[wdx];
                }
            if (Bv < -1.0e37f) Bi = 0;           // unreachable safety
            topv[k] = Bv; topi[k] = Bi;
            if (Bp >= 0) cval[Bp] = -3.0e38f;    // remove winner
        }
        __syncthreads();
    }

    if (t == 0) {
        float mx = topv[0], Z = 0.f;
        for (int k = 0; k < 32; ++k) { float w2 = expf(topv[k] - mx); wts[k] = w2; Z += w2; }
        float inv = 1.0f / Z;
        for (int k = 0; k < 32; ++k) wts[k] *= inv;
    }
    __syncthreads();

    const int v0 = t * 2;
    float2 rr = *(const float2*)(res + (size_t)row_b * 512 + v0);
    float a0 = rr.x, a1 = rr.y;
    if (useBf) {
        const u16* vt = (const u16*)vtab;
#pragma unroll
        for (int k = 0; k < 32; ++k) {
            float w2 = wts[k];
            u32 u = *(const u32*)(vt + (size_t)topi[k] * 512 + v0);
            a0 += w2 * bf2f((u16)(u & 0xffffu));
            a1 += w2 * bf2f((u16)(u >> 16));
        }
    } else {
        const float* vt = (const float*)vtab;
#pragma unroll
        for (int k = 0; k < 32; ++k) {
            float w2 = wts[k];
            float2 vv = *(const float2*)(vt + (size_t)topi[k] * 512 + v0);
            a0 += w2 * vv.x;
            a1 += w2 * vv.y;
        }
    }
    float2 o2; o2.x = a0; o2.y = a1;
    *(float2*)(out + ((size_t)row_b * 4 + s) * 512 + v0) = o2;
}

// ---------------------------------------------------------------- host

extern "C" void kernel_launch(void* const* d_in, const int* in_sizes, int n_in,
                              void* d_out, int out_size, void* d_ws, size_t ws_size,
                              hipStream_t stream)
{
    const float* x    = (const float*)d_in[0];
    const float* Wq   = (const float*)d_in[1];
    const float* bq   = (const float*)d_in[2];
    const float* keys = (const float*)d_in[3];
    const float* vals = (const float*)d_in[4];
    const float* Wr   = (const float*)d_in[5];
    const float* br   = (const float*)d_in[6];
    float* out = (float*)d_out;
    char*  ws  = (char*)d_ws;

    constexpr int BS = 4096, D = 512, KD = 256, VD = 512, S = 4, NK = 16384;

    size_t pos = 0;
    auto take = [&](size_t bytes) -> size_t {
        size_t p = (pos + 255) & ~(size_t)255; pos = p + bytes; return p;
    };
    size_t o_xbf = take((size_t)BS * D * 2);
    size_t o_wqt = take((size_t)KD * D * 2);
    size_t o_wrt = take((size_t)VD * KD * 2);
    size_t o_qbf = take((size_t)BS * KD * 2);
    size_t o_res = take((size_t)BS * VD * 4);
    size_t o_kn  = take((size_t)S * NK * KD * 2);
    size_t core_end = pos;
    size_t o_vbf = take((size_t)S * NK * VD * 2);
    bool use_vbf = (pos + (size_t)128 * NK * 2 + 512) <= ws_size;
    if (!use_vbf) pos = core_end;
    size_t rem = (ws_size > pos + 256) ? (ws_size - pos - 256) : 0;
    long long crll = (long long)(rem / ((size_t)NK * 2));
    int CR = (int)(crll > 4096 ? 4096 : crll);
    CR = (CR / 128) * 128;
    if (CR <= 0) CR = 128;
    size_t o_sc = take((size_t)CR * NK * 2);

    // prep
    k_transpose_cast<<<(D * KD + 255) / 256, 256, 0, stream>>>(Wq, (u16*)(ws + o_wqt), D, KD);
    k_transpose_cast<<<(KD * VD + 255) / 256, 256, 0, stream>>>(Wr, (u16*)(ws + o_wrt), KD, VD);
    k_cast8<<<(BS * D) / 2048, 256, 0, stream>>>(x, (u16*)(ws + o_xbf));
    if (use_vbf)
        k_cast8<<<(S * NK * VD) / 2048, 256, 0, stream>>>(vals, (u16*)(ws + o_vbf));
    k_norm_keys<<<(S * NK) / 4, 256, 0, stream>>>(keys, (u16*)(ws + o_kn));

    // q = x @ Wq + bq  (bf16 out)
    gemm_nt<1><<<dim3(KD / 128, BS / 128), 256, 0, stream>>>(
        (const short*)(ws + o_xbf), (const short*)(ws + o_wqt),
        ws + o_qbf, bq, BS, KD, D, KD);
    // res = q @ Wr + br  (f32 out)
    gemm_nt<2><<<dim3(VD / 128, BS / 128), 256, 0, stream>>>(
        (const short*)(ws + o_qbf), (const short*)(ws + o_wrt),
        ws + o_res, br, BS, VD, KD, VD);

    for (int s = 0; s < S; ++s) {
        const void* vslot = use_vbf
            ? (const void*)((u16*)(ws + o_vbf) + (size_t)s * NK * VD)
            : (const void*)(vals + (size_t)s * NK * VD);
        for (int r0 = 0; r0 < BS; r0 += CR) {
            int cr = (CR < BS - r0) ? CR : (BS - r0);
            gemm_nt<0><<<dim3(NK / 128, cr / 128), 256, 0, stream>>>(
                (const short*)(ws + o_qbf) + (size_t)r0 * KD,
                (const short*)(ws + o_kn) + (size_t)s * NK * KD,
                ws + o_sc, nullptr, cr, NK, KD, NK);
            k_select<<<cr, 256, 0, stream>>>(
                (const u16*)(ws + o_sc), vslot,
                (const float*)(ws + o_res), out, s, r0, use_vbf ? 1 : 0);
        }
    }
}